// Round 1
// baseline (730.262 us; speedup 1.0000x reference)
//
#include <hip/hip_runtime.h>
#include <math.h>

#define SEQ 4096
#define HID 1024
#define DH  64
#define NB  8

// ---------------------------------------------------------------------------
// Kernel 1: fused QKV projection.  q/k/v[row][d] = sum_h x[row][h]*W[h][d] + b
// Block = 256 threads, tile = 64 rows x 64 cols, K staged in 64-chunks.
// Thread (tx,ty) owns rows ty*4..+3, cols tx*4..+3 (4x4 per matrix, x3).
// ---------------------------------------------------------------------------
__global__ __launch_bounds__(256) void qkv_proj(
    const float* __restrict__ x,
    const float* __restrict__ Wq, const float* __restrict__ bq,
    const float* __restrict__ Wk, const float* __restrict__ bk,
    const float* __restrict__ Wv, const float* __restrict__ bv,
    float* __restrict__ qo, float* __restrict__ ko, float* __restrict__ vo)
{
    __shared__ float xs[64][68];     // +4 pad: keeps 16B align, breaks bank stride
    __shared__ float wqs[4096];
    __shared__ float wks[4096];
    __shared__ float wvs[4096];

    const int t  = threadIdx.x;
    const int tx = t & 15;
    const int ty = t >> 4;
    const int r0 = ty * 4;
    const int c0 = tx * 4;
    const int row0 = blockIdx.x * 64;

    const int rr = t >> 4;          // staging row 0..15
    const int cc = (t & 15) * 4;    // staging col 0..60

    float aq[4][4] = {{0.f}}, ak[4][4] = {{0.f}}, av[4][4] = {{0.f}};

    for (int kt = 0; kt < HID / 64; ++kt) {
        __syncthreads();
        #pragma unroll
        for (int p = 0; p < 4; ++p) {
            int r = p * 16 + rr;
            *(float4*)&xs[r][cc] =
                *(const float4*)&x[(size_t)(row0 + r) * HID + kt * 64 + cc];
        }
        const float* wqg = Wq + kt * 64 * DH;
        const float* wkg = Wk + kt * 64 * DH;
        const float* wvg = Wv + kt * 64 * DH;
        #pragma unroll
        for (int p = 0; p < 4; ++p) {
            int idx = p * 1024 + t * 4;
            *(float4*)&wqs[idx] = *(const float4*)&wqg[idx];
            *(float4*)&wks[idx] = *(const float4*)&wkg[idx];
            *(float4*)&wvs[idx] = *(const float4*)&wvg[idx];
        }
        __syncthreads();

        for (int kk = 0; kk < 64; ++kk) {
            float xv[4];
            #pragma unroll
            for (int i = 0; i < 4; ++i) xv[i] = xs[r0 + i][kk];
            float4 wq4 = *(float4*)&wqs[kk * DH + c0];
            float4 wk4 = *(float4*)&wks[kk * DH + c0];
            float4 wv4 = *(float4*)&wvs[kk * DH + c0];
            #pragma unroll
            for (int i = 0; i < 4; ++i) {
                aq[i][0] = fmaf(xv[i], wq4.x, aq[i][0]);
                aq[i][1] = fmaf(xv[i], wq4.y, aq[i][1]);
                aq[i][2] = fmaf(xv[i], wq4.z, aq[i][2]);
                aq[i][3] = fmaf(xv[i], wq4.w, aq[i][3]);
                ak[i][0] = fmaf(xv[i], wk4.x, ak[i][0]);
                ak[i][1] = fmaf(xv[i], wk4.y, ak[i][1]);
                ak[i][2] = fmaf(xv[i], wk4.z, ak[i][2]);
                ak[i][3] = fmaf(xv[i], wk4.w, ak[i][3]);
                av[i][0] = fmaf(xv[i], wv4.x, av[i][0]);
                av[i][1] = fmaf(xv[i], wv4.y, av[i][1]);
                av[i][2] = fmaf(xv[i], wv4.z, av[i][2]);
                av[i][3] = fmaf(xv[i], wv4.w, av[i][3]);
            }
        }
    }

    float4 bq4 = *(const float4*)&bq[c0];
    float4 bk4 = *(const float4*)&bk[c0];
    float4 bv4 = *(const float4*)&bv[c0];
    #pragma unroll
    for (int i = 0; i < 4; ++i) {
        size_t orow = (size_t)(row0 + r0 + i) * DH + c0;
        float4 oq = { aq[i][0] + bq4.x, aq[i][1] + bq4.y,
                      aq[i][2] + bq4.z, aq[i][3] + bq4.w };
        float4 ok = { ak[i][0] + bk4.x, ak[i][1] + bk4.y,
                      ak[i][2] + bk4.z, ak[i][3] + bk4.w };
        float4 ov = { av[i][0] + bv4.x, av[i][1] + bv4.y,
                      av[i][2] + bv4.z, av[i][3] + bv4.w };
        *(float4*)&qo[orow] = oq;
        *(float4*)&ko[orow] = ok;
        *(float4*)&vo[orow] = ov;
    }
}

// ---------------------------------------------------------------------------
// Kernel 2: causal flash attention, fp32.
// Block = 256 thr handles one batch + 64 q-rows; iterates k-tiles of 64.
// Thread (tx,ty): rows r0=ty*4..+3 (contiguous), cols {tx+16j, j=0..3}
// (strided, so 16-lane B-reads hit consecutive LDS rows -> conflict-free).
// V staged transposed so PV reads are float4 along the j (kv) axis.
// ---------------------------------------------------------------------------
__global__ __launch_bounds__(256) void attn(
    const float* __restrict__ qg, const float* __restrict__ kg,
    const float* __restrict__ vg, float* __restrict__ outg)
{
    __shared__ float qs[64][68];
    __shared__ float ks[64][68];
    __shared__ float vt[64][68];   // transposed: vt[d][j]
    __shared__ float ps[64][68];

    const int t  = threadIdx.x;
    const int tx = t & 15;
    const int ty = t >> 4;
    const int r0 = ty * 4;

    const int bx = blockIdx.x;                    // 0..63
    const int b  = blockIdx.y;                    // 0..7
    // balance causal load: blocks i and i+256 land on the same CU under
    // round-robin dispatch; (b&4) flip makes their tile-counts sum to 65.
    const int qt = (b & 4) ? (63 - bx) : bx;
    const int q0 = qt * 64;
    const size_t base = (size_t)b * SEQ * DH;

    const int rr = t >> 4;
    const int cc = (t & 15) * 4;

    #pragma unroll
    for (int p = 0; p < 4; ++p) {
        int r = p * 16 + rr;
        *(float4*)&qs[r][cc] =
            *(const float4*)&qg[base + (size_t)(q0 + r) * DH + cc];
    }

    float m[4], l[4], o[4][4];
    #pragma unroll
    for (int i = 0; i < 4; ++i) {
        m[i] = -INFINITY; l[i] = 0.f;
        #pragma unroll
        for (int j = 0; j < 4; ++j) o[i][j] = 0.f;
    }

    for (int kt = 0; kt <= qt; ++kt) {
        __syncthreads();   // prev PV done (and covers qs staging on iter 0)
        const int k0 = kt * 64;
        #pragma unroll
        for (int p = 0; p < 4; ++p) {
            int r = p * 16 + rr;
            *(float4*)&ks[r][cc] =
                *(const float4*)&kg[base + (size_t)(k0 + r) * DH + cc];
            float4 vv = *(const float4*)&vg[base + (size_t)(k0 + r) * DH + cc];
            vt[cc + 0][r] = vv.x;
            vt[cc + 1][r] = vv.y;
            vt[cc + 2][r] = vv.z;
            vt[cc + 3][r] = vv.w;
        }
        __syncthreads();

        // S = Q K^T (4x4 per thread)
        float s[4][4] = {{0.f}};
        #pragma unroll 4
        for (int d4 = 0; d4 < 16; ++d4) {
            float4 q4[4], k4[4];
            #pragma unroll
            for (int i = 0; i < 4; ++i)
                q4[i] = *(float4*)&qs[r0 + i][d4 * 4];
            #pragma unroll
            for (int j = 0; j < 4; ++j)
                k4[j] = *(float4*)&ks[tx + 16 * j][d4 * 4];
            #pragma unroll
            for (int i = 0; i < 4; ++i)
                #pragma unroll
                for (int j = 0; j < 4; ++j) {
                    s[i][j] = fmaf(q4[i].x, k4[j].x, s[i][j]);
                    s[i][j] = fmaf(q4[i].y, k4[j].y, s[i][j]);
                    s[i][j] = fmaf(q4[i].z, k4[j].z, s[i][j]);
                    s[i][j] = fmaf(q4[i].w, k4[j].w, s[i][j]);
                }
        }

        // online softmax per row (row group = 16 lanes sharing ty)
        const bool diag = (kt == qt);
        #pragma unroll
        for (int i = 0; i < 4; ++i) {
            const int qrow = q0 + r0 + i;
            float sv[4];
            float mx = -INFINITY;
            #pragma unroll
            for (int j = 0; j < 4; ++j) {
                float val = s[i][j] * 0.125f;          // 1/sqrt(64)
                if (diag && (k0 + tx + 16 * j) > qrow) val = -INFINITY;
                sv[j] = val;
                mx = fmaxf(mx, val);
            }
            #pragma unroll
            for (int off = 1; off < 16; off <<= 1)
                mx = fmaxf(mx, __shfl_xor(mx, off));
            float mn    = fmaxf(m[i], mx);
            float alpha = __expf(m[i] - mn);
            float rs    = 0.f;
            #pragma unroll
            for (int j = 0; j < 4; ++j) {
                float pv = __expf(sv[j] - mn);         // masked -> exp(-inf)=0
                ps[r0 + i][tx + 16 * j] = pv;
                rs += pv;
            }
            #pragma unroll
            for (int off = 1; off < 16; off <<= 1)
                rs += __shfl_xor(rs, off);
            l[i] = l[i] * alpha + rs;
            m[i] = mn;
            #pragma unroll
            for (int j = 0; j < 4; ++j) o[i][j] *= alpha;
        }
        __syncthreads();

        // O += P V (4x4 per thread), float4 along kv axis via ps + vt
        #pragma unroll 4
        for (int j4 = 0; j4 < 16; ++j4) {
            float4 p4[4], v4[4];
            #pragma unroll
            for (int i = 0; i < 4; ++i)
                p4[i] = *(float4*)&ps[r0 + i][j4 * 4];
            #pragma unroll
            for (int j = 0; j < 4; ++j)
                v4[j] = *(float4*)&vt[tx + 16 * j][j4 * 4];
            #pragma unroll
            for (int i = 0; i < 4; ++i)
                #pragma unroll
                for (int j = 0; j < 4; ++j) {
                    o[i][j] = fmaf(p4[i].x, v4[j].x, o[i][j]);
                    o[i][j] = fmaf(p4[i].y, v4[j].y, o[i][j]);
                    o[i][j] = fmaf(p4[i].z, v4[j].z, o[i][j]);
                    o[i][j] = fmaf(p4[i].w, v4[j].w, o[i][j]);
                }
        }
    }

    #pragma unroll
    for (int i = 0; i < 4; ++i) {
        float inv = 1.0f / l[i];
        #pragma unroll
        for (int j = 0; j < 4; ++j)
            outg[base + (size_t)(q0 + r0 + i) * DH + tx + 16 * j] = o[i][j] * inv;
    }
}

extern "C" void kernel_launch(void* const* d_in, const int* in_sizes, int n_in,
                              void* d_out, int out_size, void* d_ws, size_t ws_size,
                              hipStream_t stream) {
    const float* x  = (const float*)d_in[0];
    const float* Wq = (const float*)d_in[1];
    const float* bq = (const float*)d_in[2];
    const float* Wk = (const float*)d_in[3];
    const float* bk = (const float*)d_in[4];
    const float* Wv = (const float*)d_in[5];
    const float* bv = (const float*)d_in[6];
    float* out = (float*)d_out;

    const size_t per = (size_t)NB * SEQ * DH;   // 2,097,152 floats = 8 MB
    float* q = (float*)d_ws;
    float* k = q + per;
    float* v = k + per;

    // 32768 rows / 64 per block
    qkv_proj<<<dim3(512), 256, 0, stream>>>(x, Wq, bq, Wk, bk, Wv, bv, q, k, v);
    // one block per (q-tile, batch)
    attn<<<dim3(64, NB), 256, 0, stream>>>(q, k, v, out);
}

// Round 2
// 331.420 us; speedup vs baseline: 2.2034x; 2.2034x over previous
//
#include <hip/hip_runtime.h>
#include <hip/hip_bf16.h>
#include <math.h>

#define SEQ 4096
#define HID 1024
#define DH  64
#define NB  8

typedef unsigned short ushort_t;
typedef unsigned int   uint_t;
typedef __attribute__((ext_vector_type(8))) short           bf16x8;
typedef __attribute__((ext_vector_type(8))) unsigned short  us8;
typedef __attribute__((ext_vector_type(4))) float           f32x4;
typedef __attribute__((ext_vector_type(4))) unsigned int    u32x4;

static __device__ __forceinline__ ushort_t f2bf(float f) {
    __hip_bfloat16 h = __float2bfloat16(f);   // RNE
    return *reinterpret_cast<ushort_t*>(&h);
}

// ---------------------------------------------------------------------------
// Kernel 1: fused QKV projection via bf16 MFMA.
// C[32768 x 192] = X[32768 x 1024] * [Wq|Wk|Wv], outputs bf16 to scratch.
// Block: 256 thr (4 waves), 64-row tile, BK=64.
// Wave w owns col-tiles 3w..3w+2 (48 cols), all 4 row-tiles: 12 acc tiles.
// xs: [row][k] bf16, pad 8 (frag reads 2-way max = free).
// wt: [col][k] transposed, XOR-chunk swizzle (k-chunk ^= col>>3) to kill
//     8-way write bank conflicts from the transpose.
// ---------------------------------------------------------------------------
__global__ __launch_bounds__(256) void qkv_proj(
    const float* __restrict__ x,
    const float* __restrict__ Wq, const float* __restrict__ bq,
    const float* __restrict__ Wk, const float* __restrict__ bk,
    const float* __restrict__ Wv, const float* __restrict__ bv,
    ushort_t* __restrict__ qo, ushort_t* __restrict__ ko, ushort_t* __restrict__ vo)
{
    __shared__ ushort_t xs[64][72];
    __shared__ ushort_t wt[192][72];

    const int t  = threadIdx.x;
    const int w  = t >> 6;
    const int l  = t & 63;
    const int lr = l & 15;
    const int lg = l >> 4;
    const int row0 = blockIdx.x * 64;

    // staging assignments
    const int sxr = t >> 2;              // x: row 0..63
    const int sxc = (t & 3) * 16;        // x: 16-col chunk
    const int swc = (t & 7) * 8;         // W: 8-col chunk base
    const int swk = (t >> 3) * 2;        // W: even k row
    const int sch = (swk >> 3) ^ (t & 7);// swizzled k-chunk for writes
    const int sko = swk & 7;

    f32x4 acc[4][3];
    #pragma unroll
    for (int i = 0; i < 4; ++i)
        #pragma unroll
        for (int j = 0; j < 3; ++j)
            acc[i][j] = (f32x4){0.f, 0.f, 0.f, 0.f};

    for (int kt = 0; kt < HID / 64; ++kt) {
        const int k0g = kt * 64;
        __syncthreads();
        // --- stage X tile (fp32 -> bf16) ---
        {
            const float* xr = x + (size_t)(row0 + sxr) * HID + k0g + sxc;
            float4 a0 = *(const float4*)(xr);
            float4 a1 = *(const float4*)(xr + 4);
            float4 a2 = *(const float4*)(xr + 8);
            float4 a3 = *(const float4*)(xr + 12);
            u32x4 p0, p1;
            p0.x = (uint_t)f2bf(a0.x) | ((uint_t)f2bf(a0.y) << 16);
            p0.y = (uint_t)f2bf(a0.z) | ((uint_t)f2bf(a0.w) << 16);
            p0.z = (uint_t)f2bf(a1.x) | ((uint_t)f2bf(a1.y) << 16);
            p0.w = (uint_t)f2bf(a1.z) | ((uint_t)f2bf(a1.w) << 16);
            p1.x = (uint_t)f2bf(a2.x) | ((uint_t)f2bf(a2.y) << 16);
            p1.y = (uint_t)f2bf(a2.z) | ((uint_t)f2bf(a2.w) << 16);
            p1.z = (uint_t)f2bf(a3.x) | ((uint_t)f2bf(a3.y) << 16);
            p1.w = (uint_t)f2bf(a3.z) | ((uint_t)f2bf(a3.w) << 16);
            *(u32x4*)&xs[sxr][sxc]     = p0;
            *(u32x4*)&xs[sxr][sxc + 8] = p1;
        }
        // --- stage W tiles transposed (fp32 -> bf16, swizzled) ---
        #pragma unroll
        for (int mmat = 0; mmat < 3; ++mmat) {
            const float* Wm = (mmat == 0) ? Wq : (mmat == 1) ? Wk : Wv;
            const float* wr = Wm + (size_t)(k0g + swk) * DH + swc;
            float4 a0 = *(const float4*)(wr);
            float4 a1 = *(const float4*)(wr + 4);
            float4 b0 = *(const float4*)(wr + DH);
            float4 b1 = *(const float4*)(wr + DH + 4);
            float r0[8] = {a0.x, a0.y, a0.z, a0.w, a1.x, a1.y, a1.z, a1.w};
            float r1[8] = {b0.x, b0.y, b0.z, b0.w, b1.x, b1.y, b1.z, b1.w};
            #pragma unroll
            for (int i = 0; i < 8; ++i) {
                uint_t pk = (uint_t)f2bf(r0[i]) | ((uint_t)f2bf(r1[i]) << 16);
                *(uint_t*)&wt[mmat * 64 + swc + i][sch * 8 + sko] = pk;
            }
        }
        __syncthreads();

        // --- compute ---
        bf16x8 af[4][2];
        #pragma unroll
        for (int rt = 0; rt < 4; ++rt) {
            af[rt][0] = *(bf16x8*)&xs[rt * 16 + lr][lg * 8];
            af[rt][1] = *(bf16x8*)&xs[rt * 16 + lr][lg * 8 + 32];
        }
        #pragma unroll
        for (int ctl = 0; ctl < 3; ++ctl) {
            const int col = (w * 3 + ctl) * 16 + lr;
            const int cs  = (col >> 3) & 7;
            bf16x8 bf0 = *(bf16x8*)&wt[col][((lg + 0) ^ cs) * 8];
            bf16x8 bf1 = *(bf16x8*)&wt[col][((lg + 4) ^ cs) * 8];
            #pragma unroll
            for (int rt = 0; rt < 4; ++rt) {
                acc[rt][ctl] = __builtin_amdgcn_mfma_f32_16x16x32_bf16(
                    af[rt][0], bf0, acc[rt][ctl], 0, 0, 0);
                acc[rt][ctl] = __builtin_amdgcn_mfma_f32_16x16x32_bf16(
                    af[rt][1], bf1, acc[rt][ctl], 0, 0, 0);
            }
        }
    }

    // --- epilogue: +bias, cast bf16, store ---
    #pragma unroll
    for (int ctl = 0; ctl < 3; ++ctl) {
        const int c    = (w * 3 + ctl) * 16 + lr;
        const int mmat = c >> 6;
        const int cc   = c & 63;
        const float* bp = (mmat == 0) ? bq : (mmat == 1) ? bk : bv;
        ushort_t*    op = (mmat == 0) ? qo : (mmat == 1) ? ko : vo;
        const float bias = bp[cc];
        #pragma unroll
        for (int rt = 0; rt < 4; ++rt)
            #pragma unroll
            for (int r = 0; r < 4; ++r) {
                int row = row0 + rt * 16 + lg * 4 + r;
                op[(size_t)row * DH + cc] = f2bf(acc[rt][ctl][r] + bias);
            }
    }
}

// ---------------------------------------------------------------------------
// Kernel 2: causal flash attention, bf16 MFMA.
// Block: 256 thr (4 waves) = one (batch, 64-row q-tile); wave owns 16 q-rows.
// Q-frags in registers; K staged natural (pad 8); V staged transposed +
// XOR-chunk swizzle; P goes C-layout -> LDS -> A-layout (per-wave region).
// Longest-first block order for LPT balance.
// ---------------------------------------------------------------------------
__global__ __launch_bounds__(256) void attn(
    const ushort_t* __restrict__ qg, const ushort_t* __restrict__ kg,
    const ushort_t* __restrict__ vg, float* __restrict__ outg)
{
    __shared__ ushort_t ks[64][72];
    __shared__ ushort_t vt[64][72];
    __shared__ ushort_t ps[64][72];   // wave w owns rows 16w..16w+15

    const int t  = threadIdx.x;
    const int w  = t >> 6;
    const int l  = t & 63;
    const int lr = l & 15;
    const int lg = l >> 4;

    const int bx = blockIdx.x;            // 0..511, longest first
    const int qt = 63 - (bx >> 3);
    const int b  = bx & 7;
    const int q0 = qt * 64;
    const size_t base = (size_t)b * SEQ * DH;

    // Q fragments, once per kernel
    bf16x8 qf0, qf1;
    {
        const ushort_t* qp = qg + base + (size_t)(q0 + w * 16 + lr) * DH + lg * 8;
        qf0 = *(const bf16x8*)(qp);
        qf1 = *(const bf16x8*)(qp + 32);
    }

    float mrow[4], lrow[4];
    f32x4 o[4];
    #pragma unroll
    for (int r = 0; r < 4; ++r) { mrow[r] = -INFINITY; lrow[r] = 0.f; }
    #pragma unroll
    for (int dt = 0; dt < 4; ++dt) o[dt] = (f32x4){0.f, 0.f, 0.f, 0.f};

    const int kr  = t >> 2,        kc = (t & 3) * 16;   // K copy
    const int vj  = (t >> 3) * 2,  vd = (t & 7) * 8;    // V transpose
    const int vch = (vj >> 3) ^ (t & 7);
    const int vko = vj & 7;

    for (int kt = 0; kt <= qt; ++kt) {
        const int k0 = kt * 64;
        __syncthreads();
        // --- stage K (straight copy, bf16) ---
        {
            const ushort_t* kp = kg + base + (size_t)(k0 + kr) * DH + kc;
            *(u32x4*)&ks[kr][kc]     = *(const u32x4*)(kp);
            *(u32x4*)&ks[kr][kc + 8] = *(const u32x4*)(kp + 8);
        }
        // --- stage V transposed (swizzled) ---
        {
            const ushort_t* vp = vg + base + (size_t)(k0 + vj) * DH + vd;
            us8 r0 = *(const us8*)(vp);
            us8 r1 = *(const us8*)(vp + DH);
            #pragma unroll
            for (int i = 0; i < 8; ++i) {
                uint_t pk = (uint_t)r0[i] | ((uint_t)r1[i] << 16);
                *(uint_t*)&vt[vd + i][vch * 8 + vko] = pk;
            }
        }
        __syncthreads();

        // --- S = Q K^T ---
        f32x4 s[4];
        #pragma unroll
        for (int ct = 0; ct < 4; ++ct) s[ct] = (f32x4){0.f, 0.f, 0.f, 0.f};
        #pragma unroll
        for (int ct = 0; ct < 4; ++ct) {
            bf16x8 kf0 = *(bf16x8*)&ks[ct * 16 + lr][lg * 8];
            bf16x8 kf1 = *(bf16x8*)&ks[ct * 16 + lr][lg * 8 + 32];
            s[ct] = __builtin_amdgcn_mfma_f32_16x16x32_bf16(qf0, kf0, s[ct], 0, 0, 0);
            s[ct] = __builtin_amdgcn_mfma_f32_16x16x32_bf16(qf1, kf1, s[ct], 0, 0, 0);
        }

        // --- online softmax (row group = 16 lanes sharing lg) ---
        const bool diag = (kt == qt);
        #pragma unroll
        for (int r = 0; r < 4; ++r) {
            const int rowin = w * 16 + lg * 4 + r;
            float sv[4];
            float mx = -INFINITY;
            #pragma unroll
            for (int ct = 0; ct < 4; ++ct) {
                float v = s[ct][r] * 0.125f;              // 1/sqrt(64)
                if (diag && (ct * 16 + lr) > rowin) v = -INFINITY;
                sv[ct] = v;
                mx = fmaxf(mx, v);
            }
            mx = fmaxf(mx, __shfl_xor(mx, 1));
            mx = fmaxf(mx, __shfl_xor(mx, 2));
            mx = fmaxf(mx, __shfl_xor(mx, 4));
            mx = fmaxf(mx, __shfl_xor(mx, 8));
            const float mn = fmaxf(mrow[r], mx);
            const float al = __expf(mrow[r] - mn);
            float rs = 0.f;
            #pragma unroll
            for (int ct = 0; ct < 4; ++ct) {
                float pv = __expf(sv[ct] - mn);           // masked -> 0
                ps[w * 16 + lg * 4 + r][ct * 16 + lr] = f2bf(pv);
                rs += pv;
            }
            rs += __shfl_xor(rs, 1);
            rs += __shfl_xor(rs, 2);
            rs += __shfl_xor(rs, 4);
            rs += __shfl_xor(rs, 8);
            lrow[r] = lrow[r] * al + rs;
            mrow[r] = mn;
            #pragma unroll
            for (int dt = 0; dt < 4; ++dt) o[dt][r] *= al;
        }

        // cross-lane LDS dependence within the wave: drain DS queue
        asm volatile("s_waitcnt lgkmcnt(0)" ::: "memory");

        // --- O += P V ---
        bf16x8 pf0 = *(bf16x8*)&ps[w * 16 + lr][lg * 8];
        bf16x8 pf1 = *(bf16x8*)&ps[w * 16 + lr][lg * 8 + 32];
        #pragma unroll
        for (int dt = 0; dt < 4; ++dt) {
            const int vrow = dt * 16 + lr;
            const int cs   = (vrow >> 3) & 7;
            bf16x8 vf0 = *(bf16x8*)&vt[vrow][((lg + 0) ^ cs) * 8];
            bf16x8 vf1 = *(bf16x8*)&vt[vrow][((lg + 4) ^ cs) * 8];
            o[dt] = __builtin_amdgcn_mfma_f32_16x16x32_bf16(pf0, vf0, o[dt], 0, 0, 0);
            o[dt] = __builtin_amdgcn_mfma_f32_16x16x32_bf16(pf1, vf1, o[dt], 0, 0, 0);
        }
    }

    // --- epilogue ---
    #pragma unroll
    for (int r = 0; r < 4; ++r) {
        const float inv = 1.0f / lrow[r];
        const size_t orow = base + (size_t)(q0 + w * 16 + lg * 4 + r) * DH;
        #pragma unroll
        for (int dt = 0; dt < 4; ++dt)
            outg[orow + dt * 16 + lr] = o[dt][r] * inv;
    }
}

extern "C" void kernel_launch(void* const* d_in, const int* in_sizes, int n_in,
                              void* d_out, int out_size, void* d_ws, size_t ws_size,
                              hipStream_t stream) {
    const float* x  = (const float*)d_in[0];
    const float* Wq = (const float*)d_in[1];
    const float* bq = (const float*)d_in[2];
    const float* Wk = (const float*)d_in[3];
    const float* bk = (const float*)d_in[4];
    const float* Wv = (const float*)d_in[5];
    const float* bv = (const float*)d_in[6];
    float* out = (float*)d_out;

    const size_t per = (size_t)NB * SEQ * DH;      // 2,097,152 elems (bf16 -> 4 MB)
    ushort_t* q = (ushort_t*)d_ws;
    ushort_t* k = q + per;
    ushort_t* v = k + per;

    qkv_proj<<<dim3(512), 256, 0, stream>>>(x, Wq, bq, Wk, bk, Wv, bv, q, k, v);
    attn<<<dim3(512), 256, 0, stream>>>(q, k, v, out);
}

// Round 3
// 263.504 us; speedup vs baseline: 2.7714x; 1.2577x over previous
//
#include <hip/hip_runtime.h>
#include <hip/hip_bf16.h>
#include <math.h>

#define SEQ 4096
#define HID 1024
#define DH  64
#define NB  8
#define QSCALE 0.18033688011112042f   // 0.125 * log2(e): folds softmax scale + exp->exp2

typedef unsigned short ushort_t;
typedef unsigned int   uint_t;
typedef __attribute__((ext_vector_type(8))) short  bf16x8;
typedef __attribute__((ext_vector_type(4))) float  f32x4;
typedef __attribute__((ext_vector_type(4))) uint_t u32x4;

static __device__ __forceinline__ ushort_t f2bf(float f) {
    __hip_bfloat16 h = __float2bfloat16(f);   // RNE
    return *reinterpret_cast<ushort_t*>(&h);
}
// fast round-to-nearest bf16 (no NaN path; inputs are finite >= 0)
static __device__ __forceinline__ ushort_t f2bf_fast(float f) {
    uint_t u = __float_as_uint(f);
    return (ushort_t)((u + 0x8000u) >> 16);
}

// ---------------------------------------------------------------------------
// Kernel 0: build wts = [Wq*QSCALE | Wk | Wv] transposed to [col][k], bf16,
// pre-swizzled per 64-k tile so proj can stage it as a flat copy.
// Element (c, k): wts[(k>>6)*12288 + c*64 + (((k&63)>>3)^(c&7))*8 + (k&7)]
// ---------------------------------------------------------------------------
__global__ __launch_bounds__(256) void prep_w(
    const float* __restrict__ Wq, const float* __restrict__ Wk,
    const float* __restrict__ Wv, ushort_t* __restrict__ wts)
{
    __shared__ ushort_t tr[64][72];   // [k][c] bf16
    const int bx   = blockIdx.x;      // 48 = 3 mats x 16 k-tiles
    const int mmat = bx >> 4;
    const int kt   = bx & 15;
    const float* W  = (mmat == 0) ? Wq : (mmat == 1) ? Wk : Wv;
    const float  sc = (mmat == 0) ? QSCALE : 1.0f;

    const int t  = threadIdx.x;
    const int kr = t >> 2, kc = (t & 3) * 16;
    const float* src = W + (size_t)(kt * 64 + kr) * DH + kc;
    float4 a0 = *(const float4*)(src);
    float4 a1 = *(const float4*)(src + 4);
    float4 a2 = *(const float4*)(src + 8);
    float4 a3 = *(const float4*)(src + 12);
    float vv[16] = {a0.x,a0.y,a0.z,a0.w, a1.x,a1.y,a1.z,a1.w,
                    a2.x,a2.y,a2.z,a2.w, a3.x,a3.y,a3.z,a3.w};
    #pragma unroll
    for (int i = 0; i < 16; ++i) tr[kr][kc + i] = f2bf(vv[i] * sc);
    __syncthreads();

    const int cl = t >> 2, jc = (t & 3) * 16;
    const int c  = mmat * 64 + cl;
    ushort_t* dst = wts + kt * 12288 + c * 64;
    #pragma unroll
    for (int jj = 0; jj < 16; ++jj) {
        int j = jc + jj;
        dst[((j >> 3) ^ (cl & 7)) * 8 + (j & 7)] = tr[j][cl];
    }
}

// ---------------------------------------------------------------------------
// Kernel 1: fused QKV projection, bf16 MFMA, double-buffered (1 barrier/iter).
// Outputs: qimg natural [s][d] bf16 (Q pre-scaled by QSCALE);
//          kimg/vimg as pre-swizzled per-64-row tile images (= attn LDS image).
// ---------------------------------------------------------------------------
__global__ __launch_bounds__(256) void qkv_proj(
    const float* __restrict__ x, const ushort_t* __restrict__ wts,
    const float* __restrict__ bq, const float* __restrict__ bk,
    const float* __restrict__ bv,
    ushort_t* __restrict__ qimg, ushort_t* __restrict__ kimg,
    ushort_t* __restrict__ vimg)
{
    __shared__ ushort_t xs[2][64][72];
    __shared__ ushort_t bw[2][12288];

    const int t  = threadIdx.x;
    const int w  = t >> 6, l = t & 63, lr = l & 15, lg = l >> 4;
    const int row0 = blockIdx.x * 64;
    const int sxr = t >> 2, sxc = (t & 3) * 16;
    const int ch0 = (lg ^ (lr & 7)) * 8;
    const int ch1 = ((lg + 4) ^ (lr & 7)) * 8;

    f32x4 acc[4][3];
    #pragma unroll
    for (int i = 0; i < 4; ++i)
        #pragma unroll
        for (int j = 0; j < 3; ++j) acc[i][j] = (f32x4){0.f,0.f,0.f,0.f};

    float4 Xf[4];
    u32x4  Bf[6];
    {   // prologue: tile 0 loads
        const float* xr = x + (size_t)(row0 + sxr) * HID + sxc;
        Xf[0] = *(const float4*)(xr);      Xf[1] = *(const float4*)(xr + 4);
        Xf[2] = *(const float4*)(xr + 8);  Xf[3] = *(const float4*)(xr + 12);
        const char* bsrc = (const char*)wts + t * 16;
        #pragma unroll
        for (int i = 0; i < 6; ++i) Bf[i] = *(const u32x4*)(bsrc + i * 4096);
    }

    for (int kt = 0; kt < 16; ++kt) {
        const int buf = kt & 1;
        // A: write staged regs -> LDS buf
        {
            u32x4 p0, p1;
            p0.x = (uint_t)f2bf(Xf[0].x) | ((uint_t)f2bf(Xf[0].y) << 16);
            p0.y = (uint_t)f2bf(Xf[0].z) | ((uint_t)f2bf(Xf[0].w) << 16);
            p0.z = (uint_t)f2bf(Xf[1].x) | ((uint_t)f2bf(Xf[1].y) << 16);
            p0.w = (uint_t)f2bf(Xf[1].z) | ((uint_t)f2bf(Xf[1].w) << 16);
            p1.x = (uint_t)f2bf(Xf[2].x) | ((uint_t)f2bf(Xf[2].y) << 16);
            p1.y = (uint_t)f2bf(Xf[2].z) | ((uint_t)f2bf(Xf[2].w) << 16);
            p1.z = (uint_t)f2bf(Xf[3].x) | ((uint_t)f2bf(Xf[3].y) << 16);
            p1.w = (uint_t)f2bf(Xf[3].z) | ((uint_t)f2bf(Xf[3].w) << 16);
            *(u32x4*)&xs[buf][sxr][sxc]     = p0;
            *(u32x4*)&xs[buf][sxr][sxc + 8] = p1;
            char* bdst = (char*)&bw[buf][0] + t * 16;
            #pragma unroll
            for (int i = 0; i < 6; ++i) *(u32x4*)(bdst + i * 4096) = Bf[i];
        }
        __syncthreads();
        // C: prefetch tile kt+1 (in flight across compute)
        if (kt < 15) {
            const float* xr = x + (size_t)(row0 + sxr) * HID + (kt + 1) * 64 + sxc;
            Xf[0] = *(const float4*)(xr);      Xf[1] = *(const float4*)(xr + 4);
            Xf[2] = *(const float4*)(xr + 8);  Xf[3] = *(const float4*)(xr + 12);
            const char* bsrc = (const char*)wts + (kt + 1) * 24576 + t * 16;
            #pragma unroll
            for (int i = 0; i < 6; ++i) Bf[i] = *(const u32x4*)(bsrc + i * 4096);
        }
        // D: compute tile kt
        bf16x8 af0[4], af1[4];
        #pragma unroll
        for (int rt = 0; rt < 4; ++rt) {
            af0[rt] = *(bf16x8*)&xs[buf][rt * 16 + lr][lg * 8];
            af1[rt] = *(bf16x8*)&xs[buf][rt * 16 + lr][lg * 8 + 32];
        }
        #pragma unroll
        for (int ctl = 0; ctl < 3; ++ctl) {
            const int c = (w * 3 + ctl) * 16 + lr;
            bf16x8 b0 = *(bf16x8*)&bw[buf][c * 64 + ch0];
            bf16x8 b1 = *(bf16x8*)&bw[buf][c * 64 + ch1];
            #pragma unroll
            for (int rt = 0; rt < 4; ++rt) {
                acc[rt][ctl] = __builtin_amdgcn_mfma_f32_16x16x32_bf16(
                    af0[rt], b0, acc[rt][ctl], 0, 0, 0);
                acc[rt][ctl] = __builtin_amdgcn_mfma_f32_16x16x32_bf16(
                    af1[rt], b1, acc[rt][ctl], 0, 0, 0);
            }
        }
    }

    // epilogue: +bias, cast, scatter to layout images
    #pragma unroll
    for (int ctl = 0; ctl < 3; ++ctl) {
        const int c    = (w * 3 + ctl) * 16 + lr;
        const int mmat = c >> 6;
        const int cc   = c & 63;
        const float* bp = (mmat == 0) ? bq : (mmat == 1) ? bk : bv;
        const float bias = bp[cc] * (mmat == 0 ? QSCALE : 1.0f);
        #pragma unroll
        for (int rt = 0; rt < 4; ++rt)
            #pragma unroll
            for (int r = 0; r < 4; ++r) {
                const int s = row0 + rt * 16 + lg * 4 + r;
                const ushort_t v = f2bf(acc[rt][ctl][r] + bias);
                if (mmat == 0)
                    qimg[(size_t)s * 64 + cc] = v;
                else if (mmat == 1)
                    kimg[(size_t)(s >> 6) * 4096 + (s & 63) * 64 +
                         ((cc >> 3) ^ (s & 7)) * 8 + (cc & 7)] = v;
                else
                    vimg[(size_t)(s >> 6) * 4096 + (size_t)cc * 64 +
                         (((s & 63) >> 3) ^ (cc & 7)) * 8 + (s & 7)] = v;
            }
    }
}

// ---------------------------------------------------------------------------
// Kernel 2: causal flash attention, bf16 MFMA, double-buffered staging from
// pre-swizzled K/V tile images (flat 64 B/thread copy, 1 barrier/iter).
// No running max (scores bounded; fp32 acc can't overflow); row-sum l via
// MFMA against an all-ones B fragment (no shuffles at all).
// ---------------------------------------------------------------------------
__global__ __launch_bounds__(256) void attn(
    const ushort_t* __restrict__ qimg, const ushort_t* __restrict__ kimg,
    const ushort_t* __restrict__ vimg, float* __restrict__ outg)
{
    __shared__ ushort_t kvs[2][8192];   // [0..4095]=K tile img, [4096..8191]=V
    __shared__ ushort_t ps[64][76];     // wave w owns rows 16w..16w+15

    const int t  = threadIdx.x;
    const int w  = t >> 6, l = t & 63, lr = l & 15, lg = l >> 4;
    const int bx = blockIdx.x;          // longest-first (LPT)
    const int qt = 63 - (bx >> 3);
    const int b  = bx & 7;
    const int q0 = qt * 64;
    const int ch0 = (lg ^ (lr & 7)) * 8;
    const int ch1 = ((lg + 4) ^ (lr & 7)) * 8;

    bf16x8 qf0, qf1;
    {
        const ushort_t* qp = qimg + (size_t)(b * SEQ + q0 + w * 16 + lr) * 64 + lg * 8;
        qf0 = *(const bf16x8*)(qp);
        qf1 = *(const bf16x8*)(qp + 32);
    }
    bf16x8 ones;
    #pragma unroll
    for (int i = 0; i < 8; ++i) ones[i] = (short)0x3F80;   // bf16 1.0

    f32x4 o[4], accl;
    #pragma unroll
    for (int dt = 0; dt < 4; ++dt) o[dt] = (f32x4){0.f,0.f,0.f,0.f};
    accl = (f32x4){0.f,0.f,0.f,0.f};

    const size_t tbase = (size_t)b * 64 * 4096;   // ushort idx of batch tile 0
    u32x4 pre[4];
    {
        const char* ksrc = (const char*)(kimg + tbase);
        const char* vsrc = (const char*)(vimg + tbase);
        pre[0] = *(const u32x4*)(ksrc + t * 16);
        pre[1] = *(const u32x4*)(ksrc + t * 16 + 4096);
        pre[2] = *(const u32x4*)(vsrc + t * 16);
        pre[3] = *(const u32x4*)(vsrc + t * 16 + 4096);
    }

    for (int kt = 0; kt <= qt; ++kt) {
        const int buf = kt & 1;
        // A: stage regs -> LDS
        {
            char* dst = (char*)&kvs[buf][0] + t * 16;
            *(u32x4*)(dst)          = pre[0];
            *(u32x4*)(dst + 4096)   = pre[1];
            *(u32x4*)(dst + 8192)   = pre[2];
            *(u32x4*)(dst + 12288)  = pre[3];
        }
        __syncthreads();
        // C: prefetch next tile (flies across compute)
        if (kt < qt) {
            const char* ksrc = (const char*)(kimg + tbase) + (kt + 1) * 8192;
            const char* vsrc = (const char*)(vimg + tbase) + (kt + 1) * 8192;
            pre[0] = *(const u32x4*)(ksrc + t * 16);
            pre[1] = *(const u32x4*)(ksrc + t * 16 + 4096);
            pre[2] = *(const u32x4*)(vsrc + t * 16);
            pre[3] = *(const u32x4*)(vsrc + t * 16 + 4096);
        }
        // D: compute
        const ushort_t* kb = &kvs[buf][0];
        f32x4 s[4];
        #pragma unroll
        for (int ct = 0; ct < 4; ++ct) s[ct] = (f32x4){0.f,0.f,0.f,0.f};
        #pragma unroll
        for (int ct = 0; ct < 4; ++ct) {
            const int rowb = (ct * 16 + lr) * 64;
            bf16x8 kf0 = *(const bf16x8*)(kb + rowb + ch0);
            bf16x8 kf1 = *(const bf16x8*)(kb + rowb + ch1);
            s[ct] = __builtin_amdgcn_mfma_f32_16x16x32_bf16(qf0, kf0, s[ct], 0, 0, 0);
            s[ct] = __builtin_amdgcn_mfma_f32_16x16x32_bf16(qf1, kf1, s[ct], 0, 0, 0);
        }

        if (kt == qt) {      // diagonal tile: causal mask
            #pragma unroll
            for (int r = 0; r < 4; ++r) {
                const int qr = w * 16 + lg * 4 + r;
                #pragma unroll
                for (int ct = 0; ct < 4; ++ct) {
                    float sv = ((ct * 16 + lr) > qr) ? -INFINITY : s[ct][r];
                    float p  = __builtin_amdgcn_exp2f(sv);
                    ps[w * 16 + lg * 4 + r][ct * 16 + lr] = f2bf_fast(p);
                }
            }
        } else {
            #pragma unroll
            for (int r = 0; r < 4; ++r)
                #pragma unroll
                for (int ct = 0; ct < 4; ++ct) {
                    float p = __builtin_amdgcn_exp2f(s[ct][r]);
                    ps[w * 16 + lg * 4 + r][ct * 16 + lr] = f2bf_fast(p);
                }
        }
        asm volatile("s_waitcnt lgkmcnt(0)" ::: "memory");

        bf16x8 pf0 = *(const bf16x8*)&ps[w * 16 + lr][lg * 8];
        bf16x8 pf1 = *(const bf16x8*)&ps[w * 16 + lr][lg * 8 + 32];
        accl = __builtin_amdgcn_mfma_f32_16x16x32_bf16(pf0, ones, accl, 0, 0, 0);
        accl = __builtin_amdgcn_mfma_f32_16x16x32_bf16(pf1, ones, accl, 0, 0, 0);
        const ushort_t* vb = &kvs[buf][4096];
        #pragma unroll
        for (int dt = 0; dt < 4; ++dt) {
            const int rowb = (dt * 16 + lr) * 64;
            bf16x8 vf0 = *(const bf16x8*)(vb + rowb + ch0);
            bf16x8 vf1 = *(const bf16x8*)(vb + rowb + ch1);
            o[dt] = __builtin_amdgcn_mfma_f32_16x16x32_bf16(pf0, vf0, o[dt], 0, 0, 0);
            o[dt] = __builtin_amdgcn_mfma_f32_16x16x32_bf16(pf1, vf1, o[dt], 0, 0, 0);
        }
    }

    #pragma unroll
    for (int r = 0; r < 4; ++r) {
        const float inv = 1.0f / accl[r];
        float* orow = outg + ((size_t)b * SEQ + q0 + w * 16 + lg * 4 + r) * 64;
        #pragma unroll
        for (int dt = 0; dt < 4; ++dt)
            orow[dt * 16 + lr] = o[dt][r] * inv;
    }
}

extern "C" void kernel_launch(void* const* d_in, const int* in_sizes, int n_in,
                              void* d_out, int out_size, void* d_ws, size_t ws_size,
                              hipStream_t stream) {
    const float* x  = (const float*)d_in[0];
    const float* Wq = (const float*)d_in[1];
    const float* bq = (const float*)d_in[2];
    const float* Wk = (const float*)d_in[3];
    const float* bk = (const float*)d_in[4];
    const float* Wv = (const float*)d_in[5];
    const float* bv = (const float*)d_in[6];
    float* out = (float*)d_out;

    const size_t per = (size_t)NB * SEQ * DH;   // 2,097,152 bf16 elems = 4 MB
    ushort_t* q   = (ushort_t*)d_ws;
    ushort_t* k   = q + per;
    ushort_t* v   = k + per;
    ushort_t* wts = v + per;                    // 196,608 bf16 = 384 KB

    prep_w  <<<dim3(48),  256, 0, stream>>>(Wq, Wk, Wv, wts);
    qkv_proj<<<dim3(512), 256, 0, stream>>>(x, wts, bq, bk, bv, q, k, v);
    attn    <<<dim3(512), 256, 0, stream>>>(q, k, v, out);
}